// Round 11
// baseline (1523.046 us; speedup 1.0000x reference)
//
#include <hip/hip_runtime.h>
#include <hip/hip_bf16.h>
#include <math.h>

typedef __bf16 bf16_t;
typedef __bf16 bf16x8 __attribute__((ext_vector_type(8)));
typedef __bf16 bf16x4v __attribute__((ext_vector_type(4)));
typedef float floatx4 __attribute__((ext_vector_type(4)));

#define BM 128
#define BN 128
#define BK 64

// async global->LDS, 16B per lane. LDS dest is wave-uniform base + lane*16.
__device__ __forceinline__ void gload_lds16(const void* g, void* l) {
    __builtin_amdgcn_global_load_lds(
        (__attribute__((address_space(1))) void*)g,
        (__attribute__((address_space(3))) void*)l,
        16, 0, 0);
}

// split 8 f32 -> hi/lo bf16x8 (x ~= hi + lo, rel err ~2^-17)
__device__ __forceinline__ void split8(const float* p, bf16x8& hi, bf16x8& lo) {
    const float4* q = (const float4*)p;
    float4 a = q[0], b = q[1];
    float v[8] = { a.x, a.y, a.z, a.w, b.x, b.y, b.z, b.w };
#pragma unroll
    for (int i = 0; i < 8; ++i) {
        bf16_t h = (bf16_t)v[i];
        hi[i] = h;
        lo[i] = (bf16_t)(v[i] - (float)h);
    }
}

// ---- elementwise f32 -> (hi, lo) bf16 pair, 8 elems/thread ----
__global__ __launch_bounds__(256)
void split_pair(const float* __restrict__ x, bf16_t* __restrict__ hi,
                bf16_t* __restrict__ lo)
{
    size_t i = ((size_t)blockIdx.x * 256 + threadIdx.x) * 8;
    bf16x8 h, l;
    split8(&x[i], h, l);
    *(bf16x8*)&hi[i] = h;
    *(bf16x8*)&lo[i] = l;
}

// ======== BK=32 lean compensated K-loop (4 blocks/CU) ========
// LDS 32 KB (4 ops x 128x32 bf16); swizzle from R2 (verified):
//   stage: srow=lane>>2, source col = ((lane&3) ^ ((lane>>3)&3))<<3
//   read : col = (lg ^ ((lr>>1)&3))<<3   [(row>>1)&3 == (lr>>1)&3]
// Accumulation order per acc element: hh(k),hl(k),lh(k) over ascending
// 32-k windows — identical to the BK=64 kernels (bitwise-same results).

// ---- projections: Chi/Clo = (Ahi+Alo)(Bhi+Blo)^T + bias, split write ----
__global__ __launch_bounds__(256, 4)
void gemm_nt_proj32(const bf16_t* __restrict__ Ahi, const bf16_t* __restrict__ Alo,
                    const bf16_t* __restrict__ Bhi, const bf16_t* __restrict__ Blo,
                    const float* __restrict__ bias,
                    bf16_t* __restrict__ Chi, bf16_t* __restrict__ Clo,
                    int M, int N, int K)
{
    __shared__ bf16_t Ah[BM * 32];
    __shared__ bf16_t Al[BM * 32];
    __shared__ bf16_t Bh[BN * 32];
    __shared__ bf16_t Bl[BN * 32];

    const int t    = threadIdx.x;
    const int m0   = blockIdx.x * BM;
    const int n0   = blockIdx.y * BN;
    const int lane = t & 63;
    const int wv   = t >> 6;
    const int wm   = ((t >> 6) & 1) * 64;
    const int wn   = (t >> 7) * 64;
    const int lr   = lane & 15;
    const int lg   = lane >> 4;
    const int srow = lane >> 2;                               // 0..15 in chunk
    const int scol = ((lane & 3) ^ ((lane >> 3) & 3)) << 3;   // pre-swizzled
    const int cswz = ((lg ^ ((lr >> 1) & 3)) << 3);           // read inverse

    floatx4 acc[4][4] = {};

    for (int k0 = 0; k0 < K; k0 += 32) {
#pragma unroll
        for (int c = 0; c < 2; ++c) {
            const int chunk = wv * 2 + c;          // 8 chunks of 16 rows
            const int row   = chunk * 16 + srow;
            const size_t ga = (size_t)(m0 + row) * K + k0 + scol;
            const size_t gb = (size_t)(n0 + row) * K + k0 + scol;
            gload_lds16(&Ahi[ga], &Ah[chunk * 512]);
            gload_lds16(&Alo[ga], &Al[chunk * 512]);
            gload_lds16(&Bhi[gb], &Bh[chunk * 512]);
            gload_lds16(&Blo[gb], &Bl[chunk * 512]);
        }
        __syncthreads();
        bf16x8 ah[4], al[4];
#pragma unroll
        for (int mi = 0; mi < 4; ++mi) {
            ah[mi] = *(const bf16x8*)&Ah[(wm + mi * 16 + lr) * 32 + cswz];
            al[mi] = *(const bf16x8*)&Al[(wm + mi * 16 + lr) * 32 + cswz];
        }
#pragma unroll
        for (int ni = 0; ni < 4; ++ni) {
            bf16x8 bh = *(const bf16x8*)&Bh[(wn + ni * 16 + lr) * 32 + cswz];
            bf16x8 bl = *(const bf16x8*)&Bl[(wn + ni * 16 + lr) * 32 + cswz];
#pragma unroll
            for (int mi = 0; mi < 4; ++mi) {
                acc[mi][ni] = __builtin_amdgcn_mfma_f32_16x16x32_bf16(ah[mi], bh, acc[mi][ni], 0, 0, 0);
                acc[mi][ni] = __builtin_amdgcn_mfma_f32_16x16x32_bf16(ah[mi], bl, acc[mi][ni], 0, 0, 0);
                acc[mi][ni] = __builtin_amdgcn_mfma_f32_16x16x32_bf16(al[mi], bh, acc[mi][ni], 0, 0, 0);
            }
        }
        __syncthreads();
    }

#pragma unroll
    for (int mi = 0; mi < 4; ++mi)
#pragma unroll
        for (int ni = 0; ni < 4; ++ni) {
            int col = n0 + wn + ni * 16 + lr;
            float bv = bias[col];
#pragma unroll
            for (int r = 0; r < 4; ++r) {
                int row = m0 + wm + mi * 16 + lg * 4 + r;
                float v = acc[mi][ni][r] + bv;
                bf16_t h = (bf16_t)v;
                Chi[(size_t)row * N + col] = h;
                Clo[(size_t)row * N + col] = (bf16_t)(v - (float)h);
            }
        }
}

// ---- scores: C(f32) = (Ahi+Alo)(Bhi+Blo)^T + per-column softmax partials ----
__global__ __launch_bounds__(256, 4)
void gemm_nt_pre_async32(const bf16_t* __restrict__ Ahi, const bf16_t* __restrict__ Alo,
                         const bf16_t* __restrict__ Bhi, const bf16_t* __restrict__ Blo,
                         float* __restrict__ C, float* __restrict__ pm,
                         float* __restrict__ pz, int M, int N, int K)
{
    __shared__ bf16_t Ah[BM * 32];
    __shared__ bf16_t Al[BM * 32];
    __shared__ bf16_t Bh[BN * 32];
    __shared__ bf16_t Bl[BN * 32];
    __shared__ float red_m[2][128];
    __shared__ float red_z[2][128];

    const int t    = threadIdx.x;
    const int m0   = blockIdx.x * BM;
    const int n0   = blockIdx.y * BN;
    const int lane = t & 63;
    const int wv   = t >> 6;
    const int widm = (t >> 6) & 1;
    const int wm   = widm * 64;
    const int wn   = (t >> 7) * 64;
    const int lr   = lane & 15;
    const int lg   = lane >> 4;
    const int srow = lane >> 2;
    const int scol = ((lane & 3) ^ ((lane >> 3) & 3)) << 3;
    const int cswz = ((lg ^ ((lr >> 1) & 3)) << 3);

    floatx4 acc[4][4] = {};

    for (int k0 = 0; k0 < K; k0 += 32) {
#pragma unroll
        for (int c = 0; c < 2; ++c) {
            const int chunk = wv * 2 + c;
            const int row   = chunk * 16 + srow;
            const size_t ga = (size_t)(m0 + row) * K + k0 + scol;
            const size_t gb = (size_t)(n0 + row) * K + k0 + scol;
            gload_lds16(&Ahi[ga], &Ah[chunk * 512]);
            gload_lds16(&Alo[ga], &Al[chunk * 512]);
            gload_lds16(&Bhi[gb], &Bh[chunk * 512]);
            gload_lds16(&Blo[gb], &Bl[chunk * 512]);
        }
        __syncthreads();
        bf16x8 ah[4], al[4];
#pragma unroll
        for (int mi = 0; mi < 4; ++mi) {
            ah[mi] = *(const bf16x8*)&Ah[(wm + mi * 16 + lr) * 32 + cswz];
            al[mi] = *(const bf16x8*)&Al[(wm + mi * 16 + lr) * 32 + cswz];
        }
#pragma unroll
        for (int ni = 0; ni < 4; ++ni) {
            bf16x8 bh = *(const bf16x8*)&Bh[(wn + ni * 16 + lr) * 32 + cswz];
            bf16x8 bl = *(const bf16x8*)&Bl[(wn + ni * 16 + lr) * 32 + cswz];
#pragma unroll
            for (int mi = 0; mi < 4; ++mi) {
                acc[mi][ni] = __builtin_amdgcn_mfma_f32_16x16x32_bf16(ah[mi], bh, acc[mi][ni], 0, 0, 0);
                acc[mi][ni] = __builtin_amdgcn_mfma_f32_16x16x32_bf16(ah[mi], bl, acc[mi][ni], 0, 0, 0);
                acc[mi][ni] = __builtin_amdgcn_mfma_f32_16x16x32_bf16(al[mi], bh, acc[mi][ni], 0, 0, 0);
            }
        }
        __syncthreads();
    }

    // ---- C write ----
#pragma unroll
    for (int mi = 0; mi < 4; ++mi)
#pragma unroll
        for (int ni = 0; ni < 4; ++ni) {
            int col = n0 + wn + ni * 16 + lr;
#pragma unroll
            for (int r = 0; r < 4; ++r) {
                int row = m0 + wm + mi * 16 + lg * 4 + r;
                C[(size_t)row * N + col] = acc[mi][ni][r];
            }
        }

    // ---- per-column softmax partial over this block's 128 rows ----
#pragma unroll
    for (int ni = 0; ni < 4; ++ni) {
        float lm = -INFINITY;
#pragma unroll
        for (int mi = 0; mi < 4; ++mi)
#pragma unroll
            for (int r = 0; r < 4; ++r) lm = fmaxf(lm, acc[mi][ni][r]);
        float lz = 0.0f;
#pragma unroll
        for (int mi = 0; mi < 4; ++mi)
#pragma unroll
            for (int r = 0; r < 4; ++r) lz += __expf(acc[mi][ni][r] - lm);
#pragma unroll
        for (int off = 16; off <= 32; off <<= 1) {
            float om = __shfl_xor(lm, off);
            float oz = __shfl_xor(lz, off);
            float nm = fmaxf(lm, om);
            lz = lz * __expf(lm - nm) + oz * __expf(om - nm);
            lm = nm;
        }
        if (lg == 0) {
            red_m[widm][wn + ni * 16 + lr] = lm;
            red_z[widm][wn + ni * 16 + lr] = lz;
        }
    }
    __syncthreads();
    if (t < 128) {
        float a = red_m[0][t], b = red_m[1][t];
        float za = red_z[0][t], zb = red_z[1][t];
        float mb = fmaxf(a, b);
        float z  = za * __expf(a - mb) + zb * __expf(b - mb);
        pm[(size_t)blockIdx.x * 8192 + n0 + t] = mb;
        pz[(size_t)blockIdx.x * 8192 + n0 + t] = z;
    }
}

// ---- plain bf16 NT GEMM via global_load_lds + XOR swizzle: C(f32) = A * B^T ----
// Register-lean: acc(64) + a[4](16) + 1 live b-frag; launch_bounds(256,4)
// caps at 128 unified regs -> 4 blocks/CU. (R8 win, unchanged.)
__global__ __launch_bounds__(256, 4)
void gemm_nt_bf16_async(const bf16_t* __restrict__ A, const bf16_t* __restrict__ B,
                        float* __restrict__ C, int M, int N, int K)
{
    __shared__ bf16_t As[BM * BK];
    __shared__ bf16_t Bs[BN * BK];

    const int t    = threadIdx.x;
    const int m0   = blockIdx.x * BM;
    const int n0   = blockIdx.y * BN;
    const int lane = t & 63;
    const int wv   = t >> 6;
    const int wm   = ((t >> 6) & 1) * 64;
    const int wn   = (t >> 7) * 64;
    const int lr   = lane & 15;
    const int lg   = lane >> 4;
    const int lrow = lane >> 3;
    const int lcol = (((lane & 7) ^ lrow) * 8);
    const int swz  = (lr & 7) << 3;

    const bf16_t* aBase = A + (size_t)(m0 + wv * 32 + lrow) * K + lcol;
    const bf16_t* bBase = B + (size_t)(n0 + wv * 32 + lrow) * K + lcol;

    floatx4 acc[4][4] = {};

    for (int k0 = 0; k0 < K; k0 += BK) {
#pragma unroll
        for (int i = 0; i < 4; ++i) {
            const int seg = wv * 4 + i;
            gload_lds16(aBase + (size_t)i * 8 * K + k0, &As[seg * 512]);
            gload_lds16(bBase + (size_t)i * 8 * K + k0, &Bs[seg * 512]);
        }
        __syncthreads();
#pragma unroll
        for (int ks = 0; ks < BK; ks += 32) {
            const int cA = (ks + lg * 8) ^ swz;
            bf16x8 a0 = *(const bf16x8*)&As[(wm + 0 * 16 + lr) * BK + cA];
            bf16x8 a1 = *(const bf16x8*)&As[(wm + 1 * 16 + lr) * BK + cA];
            bf16x8 a2 = *(const bf16x8*)&As[(wm + 2 * 16 + lr) * BK + cA];
            bf16x8 a3 = *(const bf16x8*)&As[(wm + 3 * 16 + lr) * BK + cA];
#pragma unroll
            for (int ni = 0; ni < 4; ++ni) {
                bf16x8 b = *(const bf16x8*)&Bs[(wn + ni * 16 + lr) * BK + cA];
                acc[0][ni] = __builtin_amdgcn_mfma_f32_16x16x32_bf16(a0, b, acc[0][ni], 0, 0, 0);
                acc[1][ni] = __builtin_amdgcn_mfma_f32_16x16x32_bf16(a1, b, acc[1][ni], 0, 0, 0);
                acc[2][ni] = __builtin_amdgcn_mfma_f32_16x16x32_bf16(a2, b, acc[2][ni], 0, 0, 0);
                acc[3][ni] = __builtin_amdgcn_mfma_f32_16x16x32_bf16(a3, b, acc[3][ni], 0, 0, 0);
            }
        }
        __syncthreads();
    }

#pragma unroll
    for (int mi = 0; mi < 4; ++mi)
#pragma unroll
        for (int ni = 0; ni < 4; ++ni) {
            int col = n0 + wn + ni * 16 + lr;
#pragma unroll
            for (int r = 0; r < 4; ++r) {
                int row = m0 + wm + mi * 16 + lg * 4 + r;
                C[(size_t)row * N + col] = acc[mi][ni][r];
            }
        }
}

// ---- 64x64-tile transpose + f32->bf16: src [R,C] f32 -> dst [C,R] bf16 ----
__global__ __launch_bounds__(256)
void transpose_to_bf16(const float* __restrict__ src, bf16_t* __restrict__ dst,
                       int R, int Ccols)
{
    __shared__ float tile[64][65];
    const int r0 = blockIdx.x * 64;
    const int c0 = blockIdx.y * 64;
    const int tr = threadIdx.x >> 4;
    const int tc = (threadIdx.x & 15) * 4;
#pragma unroll
    for (int i = 0; i < 4; ++i) {
        int r = tr + i * 16;
        float4 v = *(const float4*)&src[(size_t)(r0 + r) * Ccols + c0 + tc];
        tile[r][tc + 0] = v.x; tile[r][tc + 1] = v.y;
        tile[r][tc + 2] = v.z; tile[r][tc + 3] = v.w;
    }
    __syncthreads();
#pragma unroll
    for (int i = 0; i < 4; ++i) {
        int c = tr + i * 16;
        bf16x4v o = { (bf16_t)tile[tc + 0][c], (bf16_t)tile[tc + 1][c],
                      (bf16_t)tile[tc + 2][c], (bf16_t)tile[tc + 3][c] };
        *(bf16x4v*)&dst[(size_t)(c0 + c) * R + r0 + tc] = o;
    }
}

// ---- column softmax combine over 64 per-block partials ----
__global__ __launch_bounds__(256)
void col_softmax_combine64(const float* __restrict__ pm, const float* __restrict__ pz,
                           float* __restrict__ mf, float* __restrict__ iz)
{
    int j = blockIdx.x * 256 + threadIdx.x;
    float m = -INFINITY;
#pragma unroll
    for (int c = 0; c < 64; ++c) m = fmaxf(m, pm[(size_t)c * 8192 + j]);
    float z = 0.0f;
#pragma unroll
    for (int c = 0; c < 64; ++c) z += pz[(size_t)c * 8192 + j] * __expf(pm[(size_t)c * 8192 + j] - m);
    mf[j] = m;
    iz[j] = 1.0f / z;
}

// normalize + also emit bf16 copy of attns for the fused GEMM
__global__ __launch_bounds__(256)
void normalize_attn_bf16(float* __restrict__ sc, const float* __restrict__ mf,
                         const float* __restrict__ iz, bf16_t* __restrict__ ab)
{
    size_t base = ((size_t)blockIdx.x * 256 + threadIdx.x) * 4;
    int j = (int)(base & 8191);
    float4 s  = *(float4*)&sc[base];
    float4 m4 = *(const float4*)&mf[j];
    float4 z4 = *(const float4*)&iz[j];
    s.x = __expf(s.x - m4.x) * z4.x;
    s.y = __expf(s.y - m4.y) * z4.y;
    s.z = __expf(s.z - m4.z) * z4.z;
    s.w = __expf(s.w - m4.w) * z4.w;
    *(float4*)&sc[base] = s;
    bf16x4v b = { (bf16_t)s.x, (bf16_t)s.y, (bf16_t)s.z, (bf16_t)s.w };
    *(bf16x4v*)&ab[base] = b;
}

extern "C" void kernel_launch(void* const* d_in, const int* in_sizes, int n_in,
                              void* d_out, int out_size, void* d_ws, size_t ws_size,
                              hipStream_t stream) {
    const float* sent  = (const float*)d_in[0];   // [8192,1024]
    const float* knowl = (const float*)d_in[1];   // [8192,2048]
    const float* Ws    = (const float*)d_in[2];   // [1024,1024]
    const float* bs    = (const float*)d_in[3];   // [1024]
    const float* Wk    = (const float*)d_in[4];   // [1024,2048]
    const float* bk    = (const float*)d_in[5];   // [1024]

    float* attns = (float*)d_out;                               // [8192,8192]
    float* fused = (float*)d_out + (size_t)8192 * 8192;         // [8192,2048]

    const size_t MB = 1024 * 1024;
    char* ws = (char*)d_ws;
    dim3 blk(256);

    // ws layout: Shi(16)@0 Slo(16)@16 Khi(16)@32 Klo(16)@48 [dead after scores]
    //            Ab(128)@0 overlays them; Vt(32)@128; pm/pz@160/162; mf/iz@164
    bf16_t* Shi = (bf16_t*)(ws + 0 * MB);
    bf16_t* Slo = (bf16_t*)(ws + 16 * MB);
    bf16_t* Khi = (bf16_t*)(ws + 32 * MB);
    bf16_t* Klo = (bf16_t*)(ws + 48 * MB);
    bf16_t* Ab  = (bf16_t*)(ws);
    bf16_t* Vt  = (bf16_t*)(ws + 128 * MB);
    float*  pm  = (float*)(ws + 160 * MB);
    float*  pz  = (float*)(ws + 162 * MB);
    float*  mf  = (float*)(ws + 164 * MB);
    float*  iz  = mf + 8192;

    // split-input scratch in d_out's attns region (dead until scores writes it)
    char* sc = (char*)attns;
    bf16_t* SEhi = (bf16_t*)(sc + 0 * MB);     // 16 MB
    bf16_t* SElo = (bf16_t*)(sc + 16 * MB);    // 16 MB
    bf16_t* KNhi = (bf16_t*)(sc + 32 * MB);    // 32 MB
    bf16_t* KNlo = (bf16_t*)(sc + 64 * MB);    // 32 MB
    bf16_t* Wshi = (bf16_t*)(sc + 96 * MB);    // 2 MB
    bf16_t* Wslo = (bf16_t*)(sc + 98 * MB);    // 2 MB
    bf16_t* Wkhi = (bf16_t*)(sc + 100 * MB);   // 4 MB
    bf16_t* Wklo = (bf16_t*)(sc + 104 * MB);   // 4 MB

    // 1) pre-split all f32 GEMM inputs into hi/lo bf16 pairs
    split_pair<<<dim3(4096), blk, 0, stream>>>(sent,  SEhi, SElo);
    split_pair<<<dim3(8192), blk, 0, stream>>>(knowl, KNhi, KNlo);
    split_pair<<<dim3(512),  blk, 0, stream>>>(Ws,    Wshi, Wslo);
    split_pair<<<dim3(1024), blk, 0, stream>>>(Wk,    Wkhi, Wklo);
    // 2) projections via BK=32 4-blocks/CU async GEMM, bias + split-write
    gemm_nt_proj32<<<dim3(64, 8), blk, 0, stream>>>(
        SEhi, SElo, Wshi, Wslo, bs, Shi, Slo, 8192, 1024, 1024);
    gemm_nt_proj32<<<dim3(64, 8), blk, 0, stream>>>(
        KNhi, KNlo, Wkhi, Wklo, bk, Khi, Klo, 8192, 1024, 2048);
    // 3) scores = S @ K^T (compensated, BK=32 4-blocks/CU) + softmax partials
    gemm_nt_pre_async32<<<dim3(64, 64), blk, 0, stream>>>(
        Shi, Slo, Khi, Klo, attns, pm, pz, 8192, 8192, 1024);
    // 4) Vt = knowl^T bf16 (overlays dead Khi/Klo)
    transpose_to_bf16<<<dim3(128, 32), blk, 0, stream>>>(knowl, Vt, 8192, 2048);
    // 5) softmax combine + normalize (also emits bf16 attns copy into Ab)
    col_softmax_combine64<<<dim3(32), blk, 0, stream>>>(pm, pz, mf, iz);
    normalize_attn_bf16<<<dim3(65536), blk, 0, stream>>>(attns, mf, iz, Ab);
    // 6) fused = attns @ V == Ab @ Vt^T
    gemm_nt_bf16_async<<<dim3(64, 16), blk, 0, stream>>>(
        Ab, Vt, fused, 8192, 2048, 8192);
}

// Round 12
// 1308.243 us; speedup vs baseline: 1.1642x; 1.1642x over previous
//
#include <hip/hip_runtime.h>
#include <hip/hip_bf16.h>
#include <math.h>

typedef __bf16 bf16_t;
typedef __bf16 bf16x8 __attribute__((ext_vector_type(8)));
typedef __bf16 bf16x4v __attribute__((ext_vector_type(4)));
typedef float floatx4 __attribute__((ext_vector_type(4)));

#define BM 128
#define BN 128
#define BK 64
#define LDT 72   // padded LDS row stride for reg-staged projection segment

// async global->LDS, 16B per lane. LDS dest is wave-uniform base + lane*16.
__device__ __forceinline__ void gload_lds16(const void* g, void* l) {
    __builtin_amdgcn_global_load_lds(
        (__attribute__((address_space(1))) void*)g,
        (__attribute__((address_space(3))) void*)l,
        16, 0, 0);
}

// split 8 f32 -> hi/lo bf16x8 (x ~= hi + lo, rel err ~2^-17)
__device__ __forceinline__ void split8(const float* p, bf16x8& hi, bf16x8& lo) {
    const float4* q = (const float4*)p;
    float4 a = q[0], b = q[1];
    float v[8] = { a.x, a.y, a.z, a.w, b.x, b.y, b.z, b.w };
#pragma unroll
    for (int i = 0; i < 8; ++i) {
        bf16_t h = (bf16_t)v[i];
        hi[i] = h;
        lo[i] = (bf16_t)(v[i] - (float)h);
    }
}

// ---- projection segment: C = A (MxK f32) * B^T (NxK f32) + bias,
// split-output (hi/lo bf16). Verified body (R7): legacy in-kernel split8. ----
__device__ void proj_segment(char* smem,
                             const float* __restrict__ A, const float* __restrict__ B,
                             const float* __restrict__ bias,
                             bf16_t* __restrict__ Chi, bf16_t* __restrict__ Clo,
                             int M, int N, int K, int bx, int by)
{
    bf16_t* Ah = (bf16_t*)smem;
    bf16_t* Al = Ah + BM * LDT;
    bf16_t* Bh = Al + BM * LDT;
    bf16_t* Bl = Bh + BN * LDT;

    const int t    = threadIdx.x;
    const int m0   = bx * BM;
    const int n0   = by * BN;
    const int lane = t & 63;
    const int wm   = ((t >> 6) & 1) * 64;
    const int wn   = (t >> 7) * 64;
    const int lr   = lane & 15;
    const int lg   = lane >> 4;

    floatx4 acc[4][4] = {};

    for (int k0 = 0; k0 < K; k0 += BK) {
#pragma unroll
        for (int i = 0; i < 4; ++i) {
            int idx = t + i * 256;
            int row = idx >> 3;
            int col = (idx & 7) << 3;
            bf16x8 h, l;
            split8(&A[(size_t)(m0 + row) * K + k0 + col], h, l);
            *(bf16x8*)&Ah[row * LDT + col] = h;
            *(bf16x8*)&Al[row * LDT + col] = l;
            split8(&B[(size_t)(n0 + row) * K + k0 + col], h, l);
            *(bf16x8*)&Bh[row * LDT + col] = h;
            *(bf16x8*)&Bl[row * LDT + col] = l;
        }
        __syncthreads();
#pragma unroll
        for (int ks = 0; ks < BK; ks += 32) {
            bf16x8 ah[4], al[4], bh[4], bl[4];
#pragma unroll
            for (int mi = 0; mi < 4; ++mi) {
                ah[mi] = *(const bf16x8*)&Ah[(wm + mi * 16 + lr) * LDT + ks + lg * 8];
                al[mi] = *(const bf16x8*)&Al[(wm + mi * 16 + lr) * LDT + ks + lg * 8];
            }
#pragma unroll
            for (int ni = 0; ni < 4; ++ni) {
                bh[ni] = *(const bf16x8*)&Bh[(wn + ni * 16 + lr) * LDT + ks + lg * 8];
                bl[ni] = *(const bf16x8*)&Bl[(wn + ni * 16 + lr) * LDT + ks + lg * 8];
            }
#pragma unroll
            for (int mi = 0; mi < 4; ++mi)
#pragma unroll
                for (int ni = 0; ni < 4; ++ni) {
                    acc[mi][ni] = __builtin_amdgcn_mfma_f32_16x16x32_bf16(ah[mi], bh[ni], acc[mi][ni], 0, 0, 0);
                    acc[mi][ni] = __builtin_amdgcn_mfma_f32_16x16x32_bf16(ah[mi], bl[ni], acc[mi][ni], 0, 0, 0);
                    acc[mi][ni] = __builtin_amdgcn_mfma_f32_16x16x32_bf16(al[mi], bh[ni], acc[mi][ni], 0, 0, 0);
                }
        }
        __syncthreads();
    }

#pragma unroll
    for (int mi = 0; mi < 4; ++mi)
#pragma unroll
        for (int ni = 0; ni < 4; ++ni) {
            int col = n0 + wn + ni * 16 + lr;
            float bv = bias[col];
#pragma unroll
            for (int r = 0; r < 4; ++r) {
                int row = m0 + wm + mi * 16 + lg * 4 + r;
                float v = acc[mi][ni][r] + bv;
                bf16_t h = (bf16_t)v;
                Chi[(size_t)row * N + col] = h;
                Clo[(size_t)row * N + col] = (bf16_t)(v - (float)h);
            }
        }
}

// ---- merged projections: proj1 (512 blk) + proj2 (512 blk), same LDS ----
// CUs finishing proj1 blocks immediately start proj2 blocks (tail overlap).
__global__ __launch_bounds__(256, 2)
void proj_fused(const float* __restrict__ sent, const float* __restrict__ Ws,
                const float* __restrict__ bs,
                const float* __restrict__ knowl, const float* __restrict__ Wk,
                const float* __restrict__ bk,
                bf16_t* __restrict__ Shi, bf16_t* __restrict__ Slo,
                bf16_t* __restrict__ Khi, bf16_t* __restrict__ Klo)
{
    __shared__ char smem[4 * BM * LDT * sizeof(bf16_t)];   // 73728 B
    const int bid = blockIdx.x;
    if (bid < 512) {
        proj_segment(smem, sent, Ws, bs, Shi, Slo, 8192, 1024, 1024,
                     bid & 63, bid >> 6);
    } else {
        const int b = bid - 512;
        proj_segment(smem, knowl, Wk, bk, Khi, Klo, 8192, 1024, 2048,
                     b & 63, b >> 6);
    }
}

// ---- pre-split NT GEMM via global_load_lds + XOR swizzle ----
// C(f32) = (Ahi+Alo)*(Bhi+Blo)^T; epilogue also emits per-column softmax
// partials (max, sumexp) over this block's 128 rows -> pm/pz[64][8192].
__global__ __launch_bounds__(256, 2)
void gemm_nt_pre_async(const bf16_t* __restrict__ Ahi, const bf16_t* __restrict__ Alo,
                       const bf16_t* __restrict__ Bhi, const bf16_t* __restrict__ Blo,
                       float* __restrict__ C, float* __restrict__ pm,
                       float* __restrict__ pz, int M, int N, int K)
{
    __shared__ bf16_t Ah[BM * BK];
    __shared__ bf16_t Al[BM * BK];
    __shared__ bf16_t Bh[BN * BK];
    __shared__ bf16_t Bl[BN * BK];
    __shared__ float red_m[2][128];
    __shared__ float red_z[2][128];

    const int t    = threadIdx.x;
    const int m0   = blockIdx.x * BM;
    const int n0   = blockIdx.y * BN;
    const int lane = t & 63;
    const int wv   = t >> 6;
    const int widm = (t >> 6) & 1;
    const int wm   = widm * 64;
    const int wn   = (t >> 7) * 64;
    const int lr   = lane & 15;
    const int lg   = lane >> 4;
    const int lrow = lane >> 3;
    const int lcol = (((lane & 7) ^ lrow) * 8);
    const int swz  = (lr & 7) << 3;

    floatx4 acc[4][4] = {};

    for (int k0 = 0; k0 < K; k0 += BK) {
#pragma unroll
        for (int i = 0; i < 4; ++i) {
            const int seg = wv * 4 + i;
            const int row = seg * 8 + lrow;
            const size_t ga = (size_t)(m0 + row) * K + k0 + lcol;
            const size_t gb = (size_t)(n0 + row) * K + k0 + lcol;
            gload_lds16(&Ahi[ga], &Ah[seg * 512]);
            gload_lds16(&Alo[ga], &Al[seg * 512]);
            gload_lds16(&Bhi[gb], &Bh[seg * 512]);
            gload_lds16(&Blo[gb], &Bl[seg * 512]);
        }
        __syncthreads();
#pragma unroll
        for (int ks = 0; ks < BK; ks += 32) {
            const int cA = (ks + lg * 8) ^ swz;
            bf16x8 ah[4], al[4], bh[4], bl[4];
#pragma unroll
            for (int mi = 0; mi < 4; ++mi) {
                ah[mi] = *(const bf16x8*)&Ah[(wm + mi * 16 + lr) * BK + cA];
                al[mi] = *(const bf16x8*)&Al[(wm + mi * 16 + lr) * BK + cA];
            }
#pragma unroll
            for (int ni = 0; ni < 4; ++ni) {
                bh[ni] = *(const bf16x8*)&Bh[(wn + ni * 16 + lr) * BK + cA];
                bl[ni] = *(const bf16x8*)&Bl[(wn + ni * 16 + lr) * BK + cA];
            }
#pragma unroll
            for (int mi = 0; mi < 4; ++mi)
#pragma unroll
                for (int ni = 0; ni < 4; ++ni) {
                    acc[mi][ni] = __builtin_amdgcn_mfma_f32_16x16x32_bf16(ah[mi], bh[ni], acc[mi][ni], 0, 0, 0);
                    acc[mi][ni] = __builtin_amdgcn_mfma_f32_16x16x32_bf16(ah[mi], bl[ni], acc[mi][ni], 0, 0, 0);
                    acc[mi][ni] = __builtin_amdgcn_mfma_f32_16x16x32_bf16(al[mi], bh[ni], acc[mi][ni], 0, 0, 0);
                }
        }
        __syncthreads();
    }

    // ---- C write ----
#pragma unroll
    for (int mi = 0; mi < 4; ++mi)
#pragma unroll
        for (int ni = 0; ni < 4; ++ni) {
            int col = n0 + wn + ni * 16 + lr;
#pragma unroll
            for (int r = 0; r < 4; ++r) {
                int row = m0 + wm + mi * 16 + lg * 4 + r;
                C[(size_t)row * N + col] = acc[mi][ni][r];
            }
        }

    // ---- per-column softmax partial over this block's 128 rows ----
#pragma unroll
    for (int ni = 0; ni < 4; ++ni) {
        float lm = -INFINITY;
#pragma unroll
        for (int mi = 0; mi < 4; ++mi)
#pragma unroll
            for (int r = 0; r < 4; ++r) lm = fmaxf(lm, acc[mi][ni][r]);
        float lz = 0.0f;
#pragma unroll
        for (int mi = 0; mi < 4; ++mi)
#pragma unroll
            for (int r = 0; r < 4; ++r) lz += __expf(acc[mi][ni][r] - lm);
#pragma unroll
        for (int off = 16; off <= 32; off <<= 1) {
            float om = __shfl_xor(lm, off);
            float oz = __shfl_xor(lz, off);
            float nm = fmaxf(lm, om);
            lz = lz * __expf(lm - nm) + oz * __expf(om - nm);
            lm = nm;
        }
        if (lg == 0) {
            red_m[widm][wn + ni * 16 + lr] = lm;
            red_z[widm][wn + ni * 16 + lr] = lz;
        }
    }
    __syncthreads();
    if (t < 128) {
        float a = red_m[0][t], b = red_m[1][t];
        float za = red_z[0][t], zb = red_z[1][t];
        float mb = fmaxf(a, b);
        float z  = za * __expf(a - mb) + zb * __expf(b - mb);
        pm[(size_t)blockIdx.x * 8192 + n0 + t] = mb;
        pz[(size_t)blockIdx.x * 8192 + n0 + t] = z;
    }
}

// ---- plain bf16 NT GEMM via global_load_lds + XOR swizzle: C(f32) = A * B^T ----
// Register-lean: acc(64) + a[4](16) + 1 live b-frag; launch_bounds(256,4)
// caps at 128 unified regs -> 4 blocks/CU. (R8 win, unchanged.)
__global__ __launch_bounds__(256, 4)
void gemm_nt_bf16_async(const bf16_t* __restrict__ A, const bf16_t* __restrict__ B,
                        float* __restrict__ C, int M, int N, int K)
{
    __shared__ bf16_t As[BM * BK];
    __shared__ bf16_t Bs[BN * BK];

    const int t    = threadIdx.x;
    const int m0   = blockIdx.x * BM;
    const int n0   = blockIdx.y * BN;
    const int lane = t & 63;
    const int wv   = t >> 6;
    const int wm   = ((t >> 6) & 1) * 64;
    const int wn   = (t >> 7) * 64;
    const int lr   = lane & 15;
    const int lg   = lane >> 4;
    const int lrow = lane >> 3;
    const int lcol = (((lane & 7) ^ lrow) * 8);
    const int swz  = (lr & 7) << 3;

    const bf16_t* aBase = A + (size_t)(m0 + wv * 32 + lrow) * K + lcol;
    const bf16_t* bBase = B + (size_t)(n0 + wv * 32 + lrow) * K + lcol;

    floatx4 acc[4][4] = {};

    for (int k0 = 0; k0 < K; k0 += BK) {
#pragma unroll
        for (int i = 0; i < 4; ++i) {
            const int seg = wv * 4 + i;
            gload_lds16(aBase + (size_t)i * 8 * K + k0, &As[seg * 512]);
            gload_lds16(bBase + (size_t)i * 8 * K + k0, &Bs[seg * 512]);
        }
        __syncthreads();
#pragma unroll
        for (int ks = 0; ks < BK; ks += 32) {
            const int cA = (ks + lg * 8) ^ swz;
            bf16x8 a0 = *(const bf16x8*)&As[(wm + 0 * 16 + lr) * BK + cA];
            bf16x8 a1 = *(const bf16x8*)&As[(wm + 1 * 16 + lr) * BK + cA];
            bf16x8 a2 = *(const bf16x8*)&As[(wm + 2 * 16 + lr) * BK + cA];
            bf16x8 a3 = *(const bf16x8*)&As[(wm + 3 * 16 + lr) * BK + cA];
#pragma unroll
            for (int ni = 0; ni < 4; ++ni) {
                bf16x8 b = *(const bf16x8*)&Bs[(wn + ni * 16 + lr) * BK + cA];
                acc[0][ni] = __builtin_amdgcn_mfma_f32_16x16x32_bf16(a0, b, acc[0][ni], 0, 0, 0);
                acc[1][ni] = __builtin_amdgcn_mfma_f32_16x16x32_bf16(a1, b, acc[1][ni], 0, 0, 0);
                acc[2][ni] = __builtin_amdgcn_mfma_f32_16x16x32_bf16(a2, b, acc[2][ni], 0, 0, 0);
                acc[3][ni] = __builtin_amdgcn_mfma_f32_16x16x32_bf16(a3, b, acc[3][ni], 0, 0, 0);
            }
        }
        __syncthreads();
    }

#pragma unroll
    for (int mi = 0; mi < 4; ++mi)
#pragma unroll
        for (int ni = 0; ni < 4; ++ni) {
            int col = n0 + wn + ni * 16 + lr;
#pragma unroll
            for (int r = 0; r < 4; ++r) {
                int row = m0 + wm + mi * 16 + lg * 4 + r;
                C[(size_t)row * N + col] = acc[mi][ni][r];
            }
        }
}

// ---- 64x64-tile transpose + f32->bf16: src [R,C] f32 -> dst [C,R] bf16 ----
__global__ __launch_bounds__(256)
void transpose_to_bf16(const float* __restrict__ src, bf16_t* __restrict__ dst,
                       int R, int Ccols)
{
    __shared__ float tile[64][65];
    const int r0 = blockIdx.x * 64;
    const int c0 = blockIdx.y * 64;
    const int tr = threadIdx.x >> 4;
    const int tc = (threadIdx.x & 15) * 4;
#pragma unroll
    for (int i = 0; i < 4; ++i) {
        int r = tr + i * 16;
        float4 v = *(const float4*)&src[(size_t)(r0 + r) * Ccols + c0 + tc];
        tile[r][tc + 0] = v.x; tile[r][tc + 1] = v.y;
        tile[r][tc + 2] = v.z; tile[r][tc + 3] = v.w;
    }
    __syncthreads();
#pragma unroll
    for (int i = 0; i < 4; ++i) {
        int c = tr + i * 16;
        bf16x4v o = { (bf16_t)tile[tc + 0][c], (bf16_t)tile[tc + 1][c],
                      (bf16_t)tile[tc + 2][c], (bf16_t)tile[tc + 3][c] };
        *(bf16x4v*)&dst[(size_t)(c0 + c) * R + r0 + tc] = o;
    }
}

// ---- column softmax combine over 64 per-block partials ----
__global__ __launch_bounds__(256)
void col_softmax_combine64(const float* __restrict__ pm, const float* __restrict__ pz,
                           float* __restrict__ mf, float* __restrict__ iz)
{
    int j = blockIdx.x * 256 + threadIdx.x;
    float m = -INFINITY;
#pragma unroll
    for (int c = 0; c < 64; ++c) m = fmaxf(m, pm[(size_t)c * 8192 + j]);
    float z = 0.0f;
#pragma unroll
    for (int c = 0; c < 64; ++c) z += pz[(size_t)c * 8192 + j] * __expf(pm[(size_t)c * 8192 + j] - m);
    mf[j] = m;
    iz[j] = 1.0f / z;
}

// normalize + also emit bf16 copy of attns for the fused GEMM
__global__ __launch_bounds__(256)
void normalize_attn_bf16(float* __restrict__ sc, const float* __restrict__ mf,
                         const float* __restrict__ iz, bf16_t* __restrict__ ab)
{
    size_t base = ((size_t)blockIdx.x * 256 + threadIdx.x) * 4;
    int j = (int)(base & 8191);
    float4 s  = *(float4*)&sc[base];
    float4 m4 = *(const float4*)&mf[j];
    float4 z4 = *(const float4*)&iz[j];
    s.x = __expf(s.x - m4.x) * z4.x;
    s.y = __expf(s.y - m4.y) * z4.y;
    s.z = __expf(s.z - m4.z) * z4.z;
    s.w = __expf(s.w - m4.w) * z4.w;
    *(float4*)&sc[base] = s;
    bf16x4v b = { (bf16_t)s.x, (bf16_t)s.y, (bf16_t)s.z, (bf16_t)s.w };
    *(bf16x4v*)&ab[base] = b;
}

extern "C" void kernel_launch(void* const* d_in, const int* in_sizes, int n_in,
                              void* d_out, int out_size, void* d_ws, size_t ws_size,
                              hipStream_t stream) {
    const float* sent  = (const float*)d_in[0];   // [8192,1024]
    const float* knowl = (const float*)d_in[1];   // [8192,2048]
    const float* Ws    = (const float*)d_in[2];   // [1024,1024]
    const float* bs    = (const float*)d_in[3];   // [1024]
    const float* Wk    = (const float*)d_in[4];   // [1024,2048]
    const float* bk    = (const float*)d_in[5];   // [1024]

    float* attns = (float*)d_out;                               // [8192,8192]
    float* fused = (float*)d_out + (size_t)8192 * 8192;         // [8192,2048]

    const size_t MB = 1024 * 1024;
    char* ws = (char*)d_ws;
    dim3 blk(256);

    // ws layout: Shi(16)@0 Slo(16)@16 Khi(16)@32 Klo(16)@48 [dead after scores]
    //            Ab(128)@0 overlays them; Vt(32)@128; pm/pz@160/162; mf/iz@164
    bf16_t* Shi = (bf16_t*)(ws + 0 * MB);
    bf16_t* Slo = (bf16_t*)(ws + 16 * MB);
    bf16_t* Khi = (bf16_t*)(ws + 32 * MB);
    bf16_t* Klo = (bf16_t*)(ws + 48 * MB);
    bf16_t* Ab  = (bf16_t*)(ws);
    bf16_t* Vt  = (bf16_t*)(ws + 128 * MB);
    float*  pm  = (float*)(ws + 160 * MB);
    float*  pz  = (float*)(ws + 162 * MB);
    float*  mf  = (float*)(ws + 164 * MB);
    float*  iz  = mf + 8192;

    // 1) merged projections: S = sent @ Ws^T + bs, K = knowl @ Wk^T + bk
    proj_fused<<<dim3(1024), blk, 0, stream>>>(
        sent, Ws, bs, knowl, Wk, bk, Shi, Slo, Khi, Klo);
    // 2) scores = S @ K^T (compensated) + per-block softmax partials
    gemm_nt_pre_async<<<dim3(64, 64), blk, 0, stream>>>(
        Shi, Slo, Khi, Klo, attns, pm, pz, 8192, 8192, 1024);
    // 3) Vt = knowl^T bf16 (overlays dead Khi/Klo)
    transpose_to_bf16<<<dim3(128, 32), blk, 0, stream>>>(knowl, Vt, 8192, 2048);
    // 4) softmax combine + normalize (also emits bf16 attns copy into Ab)
    col_softmax_combine64<<<dim3(32), blk, 0, stream>>>(pm, pz, mf, iz);
    normalize_attn_bf16<<<dim3(65536), blk, 0, stream>>>(attns, mf, iz, Ab);
    // 5) fused = attns @ V == Ab @ Vt^T
    gemm_nt_bf16_async<<<dim3(64, 16), blk, 0, stream>>>(
        Ab, Vt, fused, 8192, 2048, 8192);
}

// Round 13
// 1302.881 us; speedup vs baseline: 1.1690x; 1.0041x over previous
//
#include <hip/hip_runtime.h>
#include <hip/hip_bf16.h>
#include <math.h>

typedef __bf16 bf16_t;
typedef __bf16 bf16x8 __attribute__((ext_vector_type(8)));
typedef __bf16 bf16x4v __attribute__((ext_vector_type(4)));
typedef float floatx4 __attribute__((ext_vector_type(4)));

#define BM 128
#define BN 128
#define BK 64
#define LDT 72   // padded LDS row stride for reg-staged projection kernel

// async global->LDS, 16B per lane. LDS dest is wave-uniform base + lane*16.
__device__ __forceinline__ void gload_lds16(const void* g, void* l) {
    __builtin_amdgcn_global_load_lds(
        (__attribute__((address_space(1))) void*)g,
        (__attribute__((address_space(3))) void*)l,
        16, 0, 0);
}

// split 8 f32 -> hi/lo bf16x8 (x ~= hi + lo, rel err ~2^-17)
__device__ __forceinline__ void split8(const float* p, bf16x8& hi, bf16x8& lo) {
    const float4* q = (const float4*)p;
    float4 a = q[0], b = q[1];
    float v[8] = { a.x, a.y, a.z, a.w, b.x, b.y, b.z, b.w };
#pragma unroll
    for (int i = 0; i < 8; ++i) {
        bf16_t h = (bf16_t)v[i];
        hi[i] = h;
        lo[i] = (bf16_t)(v[i] - (float)h);
    }
}

// ---- split-precision NT GEMM: C = A (MxK f32) * B^T (NxK f32) + bias ----
// 3-term compensated bf16 MFMA: hi*hi + hi*lo + lo*hi (~f32-grade).
template<bool OUT_SPLIT, bool HAS_BIAS>
__global__ __launch_bounds__(256, 2)
void gemm_nt_split(const float* __restrict__ A, const float* __restrict__ B,
                   const float* __restrict__ bias,
                   void* __restrict__ C0, bf16_t* __restrict__ Clo,
                   int M, int N, int K)
{
    __shared__ bf16_t Ah[BM * LDT];
    __shared__ bf16_t Al[BM * LDT];
    __shared__ bf16_t Bh[BN * LDT];
    __shared__ bf16_t Bl[BN * LDT];

    const int t    = threadIdx.x;
    const int m0   = blockIdx.x * BM;
    const int n0   = blockIdx.y * BN;
    const int lane = t & 63;
    const int wm   = ((t >> 6) & 1) * 64;
    const int wn   = (t >> 7) * 64;
    const int lr   = lane & 15;
    const int lg   = lane >> 4;

    floatx4 acc[4][4] = {};

    for (int k0 = 0; k0 < K; k0 += BK) {
#pragma unroll
        for (int i = 0; i < 4; ++i) {
            int idx = t + i * 256;
            int row = idx >> 3;
            int col = (idx & 7) << 3;
            bf16x8 h, l;
            split8(&A[(size_t)(m0 + row) * K + k0 + col], h, l);
            *(bf16x8*)&Ah[row * LDT + col] = h;
            *(bf16x8*)&Al[row * LDT + col] = l;
            split8(&B[(size_t)(n0 + row) * K + k0 + col], h, l);
            *(bf16x8*)&Bh[row * LDT + col] = h;
            *(bf16x8*)&Bl[row * LDT + col] = l;
        }
        __syncthreads();
#pragma unroll
        for (int ks = 0; ks < BK; ks += 32) {
            bf16x8 ah[4], al[4], bh[4], bl[4];
#pragma unroll
            for (int mi = 0; mi < 4; ++mi) {
                ah[mi] = *(const bf16x8*)&Ah[(wm + mi * 16 + lr) * LDT + ks + lg * 8];
                al[mi] = *(const bf16x8*)&Al[(wm + mi * 16 + lr) * LDT + ks + lg * 8];
            }
#pragma unroll
            for (int ni = 0; ni < 4; ++ni) {
                bh[ni] = *(const bf16x8*)&Bh[(wn + ni * 16 + lr) * LDT + ks + lg * 8];
                bl[ni] = *(const bf16x8*)&Bl[(wn + ni * 16 + lr) * LDT + ks + lg * 8];
            }
#pragma unroll
            for (int mi = 0; mi < 4; ++mi)
#pragma unroll
                for (int ni = 0; ni < 4; ++ni) {
                    acc[mi][ni] = __builtin_amdgcn_mfma_f32_16x16x32_bf16(ah[mi], bh[ni], acc[mi][ni], 0, 0, 0);
                    acc[mi][ni] = __builtin_amdgcn_mfma_f32_16x16x32_bf16(ah[mi], bl[ni], acc[mi][ni], 0, 0, 0);
                    acc[mi][ni] = __builtin_amdgcn_mfma_f32_16x16x32_bf16(al[mi], bh[ni], acc[mi][ni], 0, 0, 0);
                }
        }
        __syncthreads();
    }

#pragma unroll
    for (int mi = 0; mi < 4; ++mi)
#pragma unroll
        for (int ni = 0; ni < 4; ++ni) {
            int col = n0 + wn + ni * 16 + lr;
            float bv = 0.0f;
            if constexpr (HAS_BIAS) bv = bias[col];
#pragma unroll
            for (int r = 0; r < 4; ++r) {
                int row = m0 + wm + mi * 16 + lg * 4 + r;
                float v = acc[mi][ni][r] + bv;
                if constexpr (OUT_SPLIT) {
                    bf16_t h = (bf16_t)v;
                    ((bf16_t*)C0)[(size_t)row * N + col] = h;
                    Clo[(size_t)row * N + col] = (bf16_t)(v - (float)h);
                } else {
                    ((float*)C0)[(size_t)row * N + col] = v;
                }
            }
        }
}

// ---- pre-split NT GEMM via global_load_lds + XOR swizzle ----
// C(f32) = (Ahi+Alo)*(Bhi+Blo)^T; epilogue also emits per-column softmax
// partials (max, sumexp) over this block's 128 rows -> pm/pz[64][8192].
__global__ __launch_bounds__(256, 2)
void gemm_nt_pre_async(const bf16_t* __restrict__ Ahi, const bf16_t* __restrict__ Alo,
                       const bf16_t* __restrict__ Bhi, const bf16_t* __restrict__ Blo,
                       float* __restrict__ C, float* __restrict__ pm,
                       float* __restrict__ pz, int M, int N, int K)
{
    __shared__ bf16_t Ah[BM * BK];
    __shared__ bf16_t Al[BM * BK];
    __shared__ bf16_t Bh[BN * BK];
    __shared__ bf16_t Bl[BN * BK];
    __shared__ float red_m[2][128];
    __shared__ float red_z[2][128];

    const int t    = threadIdx.x;
    const int m0   = blockIdx.x * BM;
    const int n0   = blockIdx.y * BN;
    const int lane = t & 63;
    const int wv   = t >> 6;
    const int widm = (t >> 6) & 1;
    const int wm   = widm * 64;
    const int wn   = (t >> 7) * 64;
    const int lr   = lane & 15;
    const int lg   = lane >> 4;
    const int lrow = lane >> 3;
    const int lcol = (((lane & 7) ^ lrow) * 8);
    const int swz  = (lr & 7) << 3;

    floatx4 acc[4][4] = {};

    for (int k0 = 0; k0 < K; k0 += BK) {
#pragma unroll
        for (int i = 0; i < 4; ++i) {
            const int seg = wv * 4 + i;
            const int row = seg * 8 + lrow;
            const size_t ga = (size_t)(m0 + row) * K + k0 + lcol;
            const size_t gb = (size_t)(n0 + row) * K + k0 + lcol;
            gload_lds16(&Ahi[ga], &Ah[seg * 512]);
            gload_lds16(&Alo[ga], &Al[seg * 512]);
            gload_lds16(&Bhi[gb], &Bh[seg * 512]);
            gload_lds16(&Blo[gb], &Bl[seg * 512]);
        }
        __syncthreads();
#pragma unroll
        for (int ks = 0; ks < BK; ks += 32) {
            const int cA = (ks + lg * 8) ^ swz;
            bf16x8 ah[4], al[4], bh[4], bl[4];
#pragma unroll
            for (int mi = 0; mi < 4; ++mi) {
                ah[mi] = *(const bf16x8*)&Ah[(wm + mi * 16 + lr) * BK + cA];
                al[mi] = *(const bf16x8*)&Al[(wm + mi * 16 + lr) * BK + cA];
            }
#pragma unroll
            for (int ni = 0; ni < 4; ++ni) {
                bh[ni] = *(const bf16x8*)&Bh[(wn + ni * 16 + lr) * BK + cA];
                bl[ni] = *(const bf16x8*)&Bl[(wn + ni * 16 + lr) * BK + cA];
            }
#pragma unroll
            for (int mi = 0; mi < 4; ++mi)
#pragma unroll
                for (int ni = 0; ni < 4; ++ni) {
                    acc[mi][ni] = __builtin_amdgcn_mfma_f32_16x16x32_bf16(ah[mi], bh[ni], acc[mi][ni], 0, 0, 0);
                    acc[mi][ni] = __builtin_amdgcn_mfma_f32_16x16x32_bf16(ah[mi], bl[ni], acc[mi][ni], 0, 0, 0);
                    acc[mi][ni] = __builtin_amdgcn_mfma_f32_16x16x32_bf16(al[mi], bh[ni], acc[mi][ni], 0, 0, 0);
                }
        }
        __syncthreads();
    }

    // ---- C write ----
#pragma unroll
    for (int mi = 0; mi < 4; ++mi)
#pragma unroll
        for (int ni = 0; ni < 4; ++ni) {
            int col = n0 + wn + ni * 16 + lr;
#pragma unroll
            for (int r = 0; r < 4; ++r) {
                int row = m0 + wm + mi * 16 + lg * 4 + r;
                C[(size_t)row * N + col] = acc[mi][ni][r];
            }
        }

    // ---- per-column softmax partial over this block's 128 rows ----
#pragma unroll
    for (int ni = 0; ni < 4; ++ni) {
        float lm = -INFINITY;
#pragma unroll
        for (int mi = 0; mi < 4; ++mi)
#pragma unroll
            for (int r = 0; r < 4; ++r) lm = fmaxf(lm, acc[mi][ni][r]);
        float lz = 0.0f;
#pragma unroll
        for (int mi = 0; mi < 4; ++mi)
#pragma unroll
            for (int r = 0; r < 4; ++r) lz += __expf(acc[mi][ni][r] - lm);
#pragma unroll
        for (int off = 16; off <= 32; off <<= 1) {
            float om = __shfl_xor(lm, off);
            float oz = __shfl_xor(lz, off);
            float nm = fmaxf(lm, om);
            lz = lz * __expf(lm - nm) + oz * __expf(om - nm);
            lm = nm;
        }
        if (lg == 0) {
            red_m[widm][wn + ni * 16 + lr] = lm;
            red_z[widm][wn + ni * 16 + lr] = lz;
        }
    }
    __syncthreads();
    if (t < 128) {
        float a = red_m[0][t], b = red_m[1][t];
        float za = red_z[0][t], zb = red_z[1][t];
        float mb = fmaxf(a, b);
        float z  = za * __expf(a - mb) + zb * __expf(b - mb);
        pm[(size_t)blockIdx.x * 8192 + n0 + t] = mb;
        pz[(size_t)blockIdx.x * 8192 + n0 + t] = z;
    }
}

// ---- plain bf16 NT GEMM via global_load_lds + XOR swizzle: C(f32) = A * B^T ----
// Register-lean: acc(64) + a[4](16) + 1 live b-frag; launch_bounds(256,4)
// caps at 128 unified regs -> 4 blocks/CU. (R8 win, unchanged.)
__global__ __launch_bounds__(256, 4)
void gemm_nt_bf16_async(const bf16_t* __restrict__ A, const bf16_t* __restrict__ B,
                        float* __restrict__ C, int M, int N, int K)
{
    __shared__ bf16_t As[BM * BK];
    __shared__ bf16_t Bs[BN * BK];

    const int t    = threadIdx.x;
    const int m0   = blockIdx.x * BM;
    const int n0   = blockIdx.y * BN;
    const int lane = t & 63;
    const int wv   = t >> 6;
    const int wm   = ((t >> 6) & 1) * 64;
    const int wn   = (t >> 7) * 64;
    const int lr   = lane & 15;
    const int lg   = lane >> 4;
    const int lrow = lane >> 3;
    const int lcol = (((lane & 7) ^ lrow) * 8);
    const int swz  = (lr & 7) << 3;

    const bf16_t* aBase = A + (size_t)(m0 + wv * 32 + lrow) * K + lcol;
    const bf16_t* bBase = B + (size_t)(n0 + wv * 32 + lrow) * K + lcol;

    floatx4 acc[4][4] = {};

    for (int k0 = 0; k0 < K; k0 += BK) {
#pragma unroll
        for (int i = 0; i < 4; ++i) {
            const int seg = wv * 4 + i;
            gload_lds16(aBase + (size_t)i * 8 * K + k0, &As[seg * 512]);
            gload_lds16(bBase + (size_t)i * 8 * K + k0, &Bs[seg * 512]);
        }
        __syncthreads();
#pragma unroll
        for (int ks = 0; ks < BK; ks += 32) {
            const int cA = (ks + lg * 8) ^ swz;
            bf16x8 a0 = *(const bf16x8*)&As[(wm + 0 * 16 + lr) * BK + cA];
            bf16x8 a1 = *(const bf16x8*)&As[(wm + 1 * 16 + lr) * BK + cA];
            bf16x8 a2 = *(const bf16x8*)&As[(wm + 2 * 16 + lr) * BK + cA];
            bf16x8 a3 = *(const bf16x8*)&As[(wm + 3 * 16 + lr) * BK + cA];
#pragma unroll
            for (int ni = 0; ni < 4; ++ni) {
                bf16x8 b = *(const bf16x8*)&Bs[(wn + ni * 16 + lr) * BK + cA];
                acc[0][ni] = __builtin_amdgcn_mfma_f32_16x16x32_bf16(a0, b, acc[0][ni], 0, 0, 0);
                acc[1][ni] = __builtin_amdgcn_mfma_f32_16x16x32_bf16(a1, b, acc[1][ni], 0, 0, 0);
                acc[2][ni] = __builtin_amdgcn_mfma_f32_16x16x32_bf16(a2, b, acc[2][ni], 0, 0, 0);
                acc[3][ni] = __builtin_amdgcn_mfma_f32_16x16x32_bf16(a3, b, acc[3][ni], 0, 0, 0);
            }
        }
        __syncthreads();
    }

#pragma unroll
    for (int mi = 0; mi < 4; ++mi)
#pragma unroll
        for (int ni = 0; ni < 4; ++ni) {
            int col = n0 + wn + ni * 16 + lr;
#pragma unroll
            for (int r = 0; r < 4; ++r) {
                int row = m0 + wm + mi * 16 + lg * 4 + r;
                C[(size_t)row * N + col] = acc[mi][ni][r];
            }
        }
}

// ---- 64x64-tile transpose + f32->bf16: src [R,C] f32 -> dst [C,R] bf16 ----
__global__ __launch_bounds__(256)
void transpose_to_bf16(const float* __restrict__ src, bf16_t* __restrict__ dst,
                       int R, int Ccols)
{
    __shared__ float tile[64][65];
    const int r0 = blockIdx.x * 64;
    const int c0 = blockIdx.y * 64;
    const int tr = threadIdx.x >> 4;
    const int tc = (threadIdx.x & 15) * 4;
#pragma unroll
    for (int i = 0; i < 4; ++i) {
        int r = tr + i * 16;
        float4 v = *(const float4*)&src[(size_t)(r0 + r) * Ccols + c0 + tc];
        tile[r][tc + 0] = v.x; tile[r][tc + 1] = v.y;
        tile[r][tc + 2] = v.z; tile[r][tc + 3] = v.w;
    }
    __syncthreads();
#pragma unroll
    for (int i = 0; i < 4; ++i) {
        int c = tr + i * 16;
        bf16x4v o = { (bf16_t)tile[tc + 0][c], (bf16_t)tile[tc + 1][c],
                      (bf16_t)tile[tc + 2][c], (bf16_t)tile[tc + 3][c] };
        *(bf16x4v*)&dst[(size_t)(c0 + c) * R + r0 + tc] = o;
    }
}

// ---- column softmax combine over 64 per-block partials ----
__global__ __launch_bounds__(256)
void col_softmax_combine64(const float* __restrict__ pm, const float* __restrict__ pz,
                           float* __restrict__ mf, float* __restrict__ iz)
{
    int j = blockIdx.x * 256 + threadIdx.x;
    float m = -INFINITY;
#pragma unroll
    for (int c = 0; c < 64; ++c) m = fmaxf(m, pm[(size_t)c * 8192 + j]);
    float z = 0.0f;
#pragma unroll
    for (int c = 0; c < 64; ++c) z += pz[(size_t)c * 8192 + j] * __expf(pm[(size_t)c * 8192 + j] - m);
    mf[j] = m;
    iz[j] = 1.0f / z;
}

// normalize + also emit bf16 copy of attns for the fused GEMM.
// Grid-stride (G11): 2048 blocks instead of 65536 micro-blocks; identical
// per-element math and store order.
__global__ __launch_bounds__(256)
void normalize_attn_bf16(float* __restrict__ sc, const float* __restrict__ mf,
                         const float* __restrict__ iz, bf16_t* __restrict__ ab)
{
    const size_t total  = (size_t)8192 * 8192;
    const size_t stride = (size_t)gridDim.x * 256 * 4;
    for (size_t base = ((size_t)blockIdx.x * 256 + threadIdx.x) * 4;
         base < total; base += stride) {
        int j = (int)(base & 8191);
        float4 s  = *(float4*)&sc[base];
        float4 m4 = *(const float4*)&mf[j];
        float4 z4 = *(const float4*)&iz[j];
        s.x = __expf(s.x - m4.x) * z4.x;
        s.y = __expf(s.y - m4.y) * z4.y;
        s.z = __expf(s.z - m4.z) * z4.z;
        s.w = __expf(s.w - m4.w) * z4.w;
        *(float4*)&sc[base] = s;
        bf16x4v b = { (bf16_t)s.x, (bf16_t)s.y, (bf16_t)s.z, (bf16_t)s.w };
        *(bf16x4v*)&ab[base] = b;
    }
}

extern "C" void kernel_launch(void* const* d_in, const int* in_sizes, int n_in,
                              void* d_out, int out_size, void* d_ws, size_t ws_size,
                              hipStream_t stream) {
    const float* sent  = (const float*)d_in[0];   // [8192,1024]
    const float* knowl = (const float*)d_in[1];   // [8192,2048]
    const float* Ws    = (const float*)d_in[2];   // [1024,1024]
    const float* bs    = (const float*)d_in[3];   // [1024]
    const float* Wk    = (const float*)d_in[4];   // [1024,2048]
    const float* bk    = (const float*)d_in[5];   // [1024]

    float* attns = (float*)d_out;                               // [8192,8192]
    float* fused = (float*)d_out + (size_t)8192 * 8192;         // [8192,2048]

    const size_t MB = 1024 * 1024;
    char* ws = (char*)d_ws;
    dim3 blk(256);

    // ws layout: Shi(16)@0 Slo(16)@16 Khi(16)@32 Klo(16)@48 [dead after scores]
    //            Ab(128)@0 overlays them; Vt(32)@128; pm/pz@160/162; mf/iz@164
    bf16_t* Shi = (bf16_t*)(ws + 0 * MB);
    bf16_t* Slo = (bf16_t*)(ws + 16 * MB);
    bf16_t* Khi = (bf16_t*)(ws + 32 * MB);
    bf16_t* Klo = (bf16_t*)(ws + 48 * MB);
    bf16_t* Ab  = (bf16_t*)(ws);
    bf16_t* Vt  = (bf16_t*)(ws + 128 * MB);
    float*  pm  = (float*)(ws + 160 * MB);
    float*  pz  = (float*)(ws + 162 * MB);
    float*  mf  = (float*)(ws + 164 * MB);
    float*  iz  = mf + 8192;

    // 1) projections: S = sent @ Ws^T + bs, K = knowl @ Wk^T + bk (split out)
    gemm_nt_split<true, true><<<dim3(64, 8), blk, 0, stream>>>(
        sent, Ws, bs, Shi, Slo, 8192, 1024, 1024);
    gemm_nt_split<true, true><<<dim3(64, 8), blk, 0, stream>>>(
        knowl, Wk, bk, Khi, Klo, 8192, 1024, 2048);
    // 2) scores = S @ K^T (compensated) + per-block softmax partials
    gemm_nt_pre_async<<<dim3(64, 64), blk, 0, stream>>>(
        Shi, Slo, Khi, Klo, attns, pm, pz, 8192, 8192, 1024);
    // 3) Vt = knowl^T bf16 (overlays dead Khi/Klo)
    transpose_to_bf16<<<dim3(128, 32), blk, 0, stream>>>(knowl, Vt, 8192, 2048);
    // 4) softmax combine + normalize (also emits bf16 attns copy into Ab)
    col_softmax_combine64<<<dim3(32), blk, 0, stream>>>(pm, pz, mf, iz);
    normalize_attn_bf16<<<dim3(2048), blk, 0, stream>>>(attns, mf, iz, Ab);
    // 5) fused = attns @ V == Ab @ Vt^T
    gemm_nt_bf16_async<<<dim3(64, 16), blk, 0, stream>>>(
        Ab, Vt, fused, 8192, 2048, 8192);
}

// Round 14
// 1268.833 us; speedup vs baseline: 1.2004x; 1.0268x over previous
//
#include <hip/hip_runtime.h>
#include <hip/hip_bf16.h>
#include <math.h>

typedef __bf16 bf16_t;
typedef __bf16 bf16x8 __attribute__((ext_vector_type(8)));
typedef __bf16 bf16x4v __attribute__((ext_vector_type(4)));
typedef float floatx4 __attribute__((ext_vector_type(4)));

#define BM 128
#define BN 128
#define BK 64
#define LDT 72   // padded LDS row stride for reg-staged projection kernel

// async global->LDS, 16B per lane. LDS dest is wave-uniform base + lane*16.
__device__ __forceinline__ void gload_lds16(const void* g, void* l) {
    __builtin_amdgcn_global_load_lds(
        (__attribute__((address_space(1))) void*)g,
        (__attribute__((address_space(3))) void*)l,
        16, 0, 0);
}

// split 8 f32 -> hi/lo bf16x8 (x ~= hi + lo, rel err ~2^-17)
__device__ __forceinline__ void split8(const float* p, bf16x8& hi, bf16x8& lo) {
    const float4* q = (const float4*)p;
    float4 a = q[0], b = q[1];
    float v[8] = { a.x, a.y, a.z, a.w, b.x, b.y, b.z, b.w };
#pragma unroll
    for (int i = 0; i < 8; ++i) {
        bf16_t h = (bf16_t)v[i];
        hi[i] = h;
        lo[i] = (bf16_t)(v[i] - (float)h);
    }
}

// ---- split-precision NT GEMM: C = A (MxK f32) * B^T (NxK f32) + bias ----
// 3-term compensated bf16 MFMA: hi*hi + hi*lo + lo*hi (~f32-grade).
template<bool OUT_SPLIT, bool HAS_BIAS>
__global__ __launch_bounds__(256, 2)
void gemm_nt_split(const float* __restrict__ A, const float* __restrict__ B,
                   const float* __restrict__ bias,
                   void* __restrict__ C0, bf16_t* __restrict__ Clo,
                   int M, int N, int K)
{
    __shared__ bf16_t Ah[BM * LDT];
    __shared__ bf16_t Al[BM * LDT];
    __shared__ bf16_t Bh[BN * LDT];
    __shared__ bf16_t Bl[BN * LDT];

    const int t    = threadIdx.x;
    const int m0   = blockIdx.x * BM;
    const int n0   = blockIdx.y * BN;
    const int lane = t & 63;
    const int wm   = ((t >> 6) & 1) * 64;
    const int wn   = (t >> 7) * 64;
    const int lr   = lane & 15;
    const int lg   = lane >> 4;

    floatx4 acc[4][4] = {};

    for (int k0 = 0; k0 < K; k0 += BK) {
#pragma unroll
        for (int i = 0; i < 4; ++i) {
            int idx = t + i * 256;
            int row = idx >> 3;
            int col = (idx & 7) << 3;
            bf16x8 h, l;
            split8(&A[(size_t)(m0 + row) * K + k0 + col], h, l);
            *(bf16x8*)&Ah[row * LDT + col] = h;
            *(bf16x8*)&Al[row * LDT + col] = l;
            split8(&B[(size_t)(n0 + row) * K + k0 + col], h, l);
            *(bf16x8*)&Bh[row * LDT + col] = h;
            *(bf16x8*)&Bl[row * LDT + col] = l;
        }
        __syncthreads();
#pragma unroll
        for (int ks = 0; ks < BK; ks += 32) {
            bf16x8 ah[4], al[4], bh[4], bl[4];
#pragma unroll
            for (int mi = 0; mi < 4; ++mi) {
                ah[mi] = *(const bf16x8*)&Ah[(wm + mi * 16 + lr) * LDT + ks + lg * 8];
                al[mi] = *(const bf16x8*)&Al[(wm + mi * 16 + lr) * LDT + ks + lg * 8];
            }
#pragma unroll
            for (int ni = 0; ni < 4; ++ni) {
                bh[ni] = *(const bf16x8*)&Bh[(wn + ni * 16 + lr) * LDT + ks + lg * 8];
                bl[ni] = *(const bf16x8*)&Bl[(wn + ni * 16 + lr) * LDT + ks + lg * 8];
            }
#pragma unroll
            for (int mi = 0; mi < 4; ++mi)
#pragma unroll
                for (int ni = 0; ni < 4; ++ni) {
                    acc[mi][ni] = __builtin_amdgcn_mfma_f32_16x16x32_bf16(ah[mi], bh[ni], acc[mi][ni], 0, 0, 0);
                    acc[mi][ni] = __builtin_amdgcn_mfma_f32_16x16x32_bf16(ah[mi], bl[ni], acc[mi][ni], 0, 0, 0);
                    acc[mi][ni] = __builtin_amdgcn_mfma_f32_16x16x32_bf16(al[mi], bh[ni], acc[mi][ni], 0, 0, 0);
                }
        }
        __syncthreads();
    }

#pragma unroll
    for (int mi = 0; mi < 4; ++mi)
#pragma unroll
        for (int ni = 0; ni < 4; ++ni) {
            int col = n0 + wn + ni * 16 + lr;
            float bv = 0.0f;
            if constexpr (HAS_BIAS) bv = bias[col];
#pragma unroll
            for (int r = 0; r < 4; ++r) {
                int row = m0 + wm + mi * 16 + lg * 4 + r;
                float v = acc[mi][ni][r] + bv;
                if constexpr (OUT_SPLIT) {
                    bf16_t h = (bf16_t)v;
                    ((bf16_t*)C0)[(size_t)row * N + col] = h;
                    Clo[(size_t)row * N + col] = (bf16_t)(v - (float)h);
                } else {
                    ((float*)C0)[(size_t)row * N + col] = v;
                }
            }
        }
}

// ---- pre-split NT GEMM via global_load_lds + XOR swizzle ----
// C(f32) = (Ahi+Alo)*(Bhi+Blo)^T; epilogue also emits per-column softmax
// partials (max, sumexp) over this block's 128 rows -> pm/pz[64][8192].
__global__ __launch_bounds__(256, 2)
void gemm_nt_pre_async(const bf16_t* __restrict__ Ahi, const bf16_t* __restrict__ Alo,
                       const bf16_t* __restrict__ Bhi, const bf16_t* __restrict__ Blo,
                       float* __restrict__ C, float* __restrict__ pm,
                       float* __restrict__ pz, int M, int N, int K)
{
    __shared__ bf16_t Ah[BM * BK];
    __shared__ bf16_t Al[BM * BK];
    __shared__ bf16_t Bh[BN * BK];
    __shared__ bf16_t Bl[BN * BK];
    __shared__ float red_m[2][128];
    __shared__ float red_z[2][128];

    const int t    = threadIdx.x;
    const int m0   = blockIdx.x * BM;
    const int n0   = blockIdx.y * BN;
    const int lane = t & 63;
    const int wv   = t >> 6;
    const int widm = (t >> 6) & 1;
    const int wm   = widm * 64;
    const int wn   = (t >> 7) * 64;
    const int lr   = lane & 15;
    const int lg   = lane >> 4;
    const int lrow = lane >> 3;
    const int lcol = (((lane & 7) ^ lrow) * 8);
    const int swz  = (lr & 7) << 3;

    floatx4 acc[4][4] = {};

    for (int k0 = 0; k0 < K; k0 += BK) {
#pragma unroll
        for (int i = 0; i < 4; ++i) {
            const int seg = wv * 4 + i;
            const int row = seg * 8 + lrow;
            const size_t ga = (size_t)(m0 + row) * K + k0 + lcol;
            const size_t gb = (size_t)(n0 + row) * K + k0 + lcol;
            gload_lds16(&Ahi[ga], &Ah[seg * 512]);
            gload_lds16(&Alo[ga], &Al[seg * 512]);
            gload_lds16(&Bhi[gb], &Bh[seg * 512]);
            gload_lds16(&Blo[gb], &Bl[seg * 512]);
        }
        __syncthreads();
#pragma unroll
        for (int ks = 0; ks < BK; ks += 32) {
            const int cA = (ks + lg * 8) ^ swz;
            bf16x8 ah[4], al[4], bh[4], bl[4];
#pragma unroll
            for (int mi = 0; mi < 4; ++mi) {
                ah[mi] = *(const bf16x8*)&Ah[(wm + mi * 16 + lr) * BK + cA];
                al[mi] = *(const bf16x8*)&Al[(wm + mi * 16 + lr) * BK + cA];
            }
#pragma unroll
            for (int ni = 0; ni < 4; ++ni) {
                bh[ni] = *(const bf16x8*)&Bh[(wn + ni * 16 + lr) * BK + cA];
                bl[ni] = *(const bf16x8*)&Bl[(wn + ni * 16 + lr) * BK + cA];
            }
#pragma unroll
            for (int mi = 0; mi < 4; ++mi)
#pragma unroll
                for (int ni = 0; ni < 4; ++ni) {
                    acc[mi][ni] = __builtin_amdgcn_mfma_f32_16x16x32_bf16(ah[mi], bh[ni], acc[mi][ni], 0, 0, 0);
                    acc[mi][ni] = __builtin_amdgcn_mfma_f32_16x16x32_bf16(ah[mi], bl[ni], acc[mi][ni], 0, 0, 0);
                    acc[mi][ni] = __builtin_amdgcn_mfma_f32_16x16x32_bf16(al[mi], bh[ni], acc[mi][ni], 0, 0, 0);
                }
        }
        __syncthreads();
    }

    // ---- C write ----
#pragma unroll
    for (int mi = 0; mi < 4; ++mi)
#pragma unroll
        for (int ni = 0; ni < 4; ++ni) {
            int col = n0 + wn + ni * 16 + lr;
#pragma unroll
            for (int r = 0; r < 4; ++r) {
                int row = m0 + wm + mi * 16 + lg * 4 + r;
                C[(size_t)row * N + col] = acc[mi][ni][r];
            }
        }

    // ---- per-column softmax partial over this block's 128 rows ----
#pragma unroll
    for (int ni = 0; ni < 4; ++ni) {
        float lm = -INFINITY;
#pragma unroll
        for (int mi = 0; mi < 4; ++mi)
#pragma unroll
            for (int r = 0; r < 4; ++r) lm = fmaxf(lm, acc[mi][ni][r]);
        float lz = 0.0f;
#pragma unroll
        for (int mi = 0; mi < 4; ++mi)
#pragma unroll
            for (int r = 0; r < 4; ++r) lz += __expf(acc[mi][ni][r] - lm);
#pragma unroll
        for (int off = 16; off <= 32; off <<= 1) {
            float om = __shfl_xor(lm, off);
            float oz = __shfl_xor(lz, off);
            float nm = fmaxf(lm, om);
            lz = lz * __expf(lm - nm) + oz * __expf(om - nm);
            lm = nm;
        }
        if (lg == 0) {
            red_m[widm][wn + ni * 16 + lr] = lm;
            red_z[widm][wn + ni * 16 + lr] = lz;
        }
    }
    __syncthreads();
    if (t < 128) {
        float a = red_m[0][t], b = red_m[1][t];
        float za = red_z[0][t], zb = red_z[1][t];
        float mb = fmaxf(a, b);
        float z  = za * __expf(a - mb) + zb * __expf(b - mb);
        pm[(size_t)blockIdx.x * 8192 + n0 + t] = mb;
        pz[(size_t)blockIdx.x * 8192 + n0 + t] = z;
    }
}

// ---- plain bf16 NT GEMM via global_load_lds + XOR swizzle: C(f32) = A * B^T ----
// Register-lean: acc(64) + a[4](16) + 1 live b-frag; launch_bounds(256,4)
// caps at 128 unified regs -> 4 blocks/CU. (R8 win.)
__global__ __launch_bounds__(256, 4)
void gemm_nt_bf16_async(const bf16_t* __restrict__ A, const bf16_t* __restrict__ B,
                        float* __restrict__ C, int M, int N, int K)
{
    __shared__ bf16_t As[BM * BK];
    __shared__ bf16_t Bs[BN * BK];

    const int t    = threadIdx.x;
    const int m0   = blockIdx.x * BM;
    const int n0   = blockIdx.y * BN;
    const int lane = t & 63;
    const int wv   = t >> 6;
    const int wm   = ((t >> 6) & 1) * 64;
    const int wn   = (t >> 7) * 64;
    const int lr   = lane & 15;
    const int lg   = lane >> 4;
    const int lrow = lane >> 3;
    const int lcol = (((lane & 7) ^ lrow) * 8);
    const int swz  = (lr & 7) << 3;

    const bf16_t* aBase = A + (size_t)(m0 + wv * 32 + lrow) * K + lcol;
    const bf16_t* bBase = B + (size_t)(n0 + wv * 32 + lrow) * K + lcol;

    floatx4 acc[4][4] = {};

    for (int k0 = 0; k0 < K; k0 += BK) {
#pragma unroll
        for (int i = 0; i < 4; ++i) {
            const int seg = wv * 4 + i;
            gload_lds16(aBase + (size_t)i * 8 * K + k0, &As[seg * 512]);
            gload_lds16(bBase + (size_t)i * 8 * K + k0, &Bs[seg * 512]);
        }
        __syncthreads();
#pragma unroll
        for (int ks = 0; ks < BK; ks += 32) {
            const int cA = (ks + lg * 8) ^ swz;
            bf16x8 a0 = *(const bf16x8*)&As[(wm + 0 * 16 + lr) * BK + cA];
            bf16x8 a1 = *(const bf16x8*)&As[(wm + 1 * 16 + lr) * BK + cA];
            bf16x8 a2 = *(const bf16x8*)&As[(wm + 2 * 16 + lr) * BK + cA];
            bf16x8 a3 = *(const bf16x8*)&As[(wm + 3 * 16 + lr) * BK + cA];
#pragma unroll
            for (int ni = 0; ni < 4; ++ni) {
                bf16x8 b = *(const bf16x8*)&Bs[(wn + ni * 16 + lr) * BK + cA];
                acc[0][ni] = __builtin_amdgcn_mfma_f32_16x16x32_bf16(a0, b, acc[0][ni], 0, 0, 0);
                acc[1][ni] = __builtin_amdgcn_mfma_f32_16x16x32_bf16(a1, b, acc[1][ni], 0, 0, 0);
                acc[2][ni] = __builtin_amdgcn_mfma_f32_16x16x32_bf16(a2, b, acc[2][ni], 0, 0, 0);
                acc[3][ni] = __builtin_amdgcn_mfma_f32_16x16x32_bf16(a3, b, acc[3][ni], 0, 0, 0);
            }
        }
        __syncthreads();
    }

#pragma unroll
    for (int mi = 0; mi < 4; ++mi)
#pragma unroll
        for (int ni = 0; ni < 4; ++ni) {
            int col = n0 + wn + ni * 16 + lr;
#pragma unroll
            for (int r = 0; r < 4; ++r) {
                int row = m0 + wm + mi * 16 + lg * 4 + r;
                C[(size_t)row * N + col] = acc[mi][ni][r];
            }
        }
}

// ---- 64x64-tile transpose + f32->bf16: src [R,C] f32 -> dst [C,R] bf16 ----
__global__ __launch_bounds__(256)
void transpose_to_bf16(const float* __restrict__ src, bf16_t* __restrict__ dst,
                       int R, int Ccols)
{
    __shared__ float tile[64][65];
    const int r0 = blockIdx.x * 64;
    const int c0 = blockIdx.y * 64;
    const int tr = threadIdx.x >> 4;
    const int tc = (threadIdx.x & 15) * 4;
#pragma unroll
    for (int i = 0; i < 4; ++i) {
        int r = tr + i * 16;
        float4 v = *(const float4*)&src[(size_t)(r0 + r) * Ccols + c0 + tc];
        tile[r][tc + 0] = v.x; tile[r][tc + 1] = v.y;
        tile[r][tc + 2] = v.z; tile[r][tc + 3] = v.w;
    }
    __syncthreads();
#pragma unroll
    for (int i = 0; i < 4; ++i) {
        int c = tr + i * 16;
        bf16x4v o = { (bf16_t)tile[tc + 0][c], (bf16_t)tile[tc + 1][c],
                      (bf16_t)tile[tc + 2][c], (bf16_t)tile[tc + 3][c] };
        *(bf16x4v*)&dst[(size_t)(c0 + c) * R + r0 + tc] = o;
    }
}

// ---- column softmax combine over 64 per-block partials ----
__global__ __launch_bounds__(256)
void col_softmax_combine64(const float* __restrict__ pm, const float* __restrict__ pz,
                           float* __restrict__ mf, float* __restrict__ iz)
{
    int j = blockIdx.x * 256 + threadIdx.x;
    float m = -INFINITY;
#pragma unroll
    for (int c = 0; c < 64; ++c) m = fmaxf(m, pm[(size_t)c * 8192 + j]);
    float z = 0.0f;
#pragma unroll
    for (int c = 0; c < 64; ++c) z += pz[(size_t)c * 8192 + j] * __expf(pm[(size_t)c * 8192 + j] - m);
    mf[j] = m;
    iz[j] = 1.0f / z;
}

// normalize + also emit bf16 copy of attns for the fused GEMM (R8 form)
__global__ __launch_bounds__(256)
void normalize_attn_bf16(float* __restrict__ sc, const float* __restrict__ mf,
                         const float* __restrict__ iz, bf16_t* __restrict__ ab)
{
    size_t base = ((size_t)blockIdx.x * 256 + threadIdx.x) * 4;
    int j = (int)(base & 8191);
    float4 s  = *(float4*)&sc[base];
    float4 m4 = *(const float4*)&mf[j];
    float4 z4 = *(const float4*)&iz[j];
    s.x = __expf(s.x - m4.x) * z4.x;
    s.y = __expf(s.y - m4.y) * z4.y;
    s.z = __expf(s.z - m4.z) * z4.z;
    s.w = __expf(s.w - m4.w) * z4.w;
    *(float4*)&sc[base] = s;
    bf16x4v b = { (bf16_t)s.x, (bf16_t)s.y, (bf16_t)s.z, (bf16_t)s.w };
    *(bf16x4v*)&ab[base] = b;
}

extern "C" void kernel_launch(void* const* d_in, const int* in_sizes, int n_in,
                              void* d_out, int out_size, void* d_ws, size_t ws_size,
                              hipStream_t stream) {
    const float* sent  = (const float*)d_in[0];   // [8192,1024]
    const float* knowl = (const float*)d_in[1];   // [8192,2048]
    const float* Ws    = (const float*)d_in[2];   // [1024,1024]
    const float* bs    = (const float*)d_in[3];   // [1024]
    const float* Wk    = (const float*)d_in[4];   // [1024,2048]
    const float* bk    = (const float*)d_in[5];   // [1024]

    float* attns = (float*)d_out;                               // [8192,8192]
    float* fused = (float*)d_out + (size_t)8192 * 8192;         // [8192,2048]

    const size_t MB = 1024 * 1024;
    char* ws = (char*)d_ws;
    dim3 blk(256);

    // ws layout: Shi(16)@0 Slo(16)@16 Khi(16)@32 Klo(16)@48 [dead after scores]
    //            Ab(128)@0 overlays them; Vt(32)@128; pm/pz@160/162; mf/iz@164
    bf16_t* Shi = (bf16_t*)(ws + 0 * MB);
    bf16_t* Slo = (bf16_t*)(ws + 16 * MB);
    bf16_t* Khi = (bf16_t*)(ws + 32 * MB);
    bf16_t* Klo = (bf16_t*)(ws + 48 * MB);
    bf16_t* Ab  = (bf16_t*)(ws);
    bf16_t* Vt  = (bf16_t*)(ws + 128 * MB);
    float*  pm  = (float*)(ws + 160 * MB);
    float*  pz  = (float*)(ws + 162 * MB);
    float*  mf  = (float*)(ws + 164 * MB);
    float*  iz  = mf + 8192;

    // 1) projections: S = sent @ Ws^T + bs, K = knowl @ Wk^T + bk (split out)
    gemm_nt_split<true, true><<<dim3(64, 8), blk, 0, stream>>>(
        sent, Ws, bs, Shi, Slo, 8192, 1024, 1024);
    gemm_nt_split<true, true><<<dim3(64, 8), blk, 0, stream>>>(
        knowl, Wk, bk, Khi, Klo, 8192, 1024, 2048);
    // 2) scores = S @ K^T (compensated) + per-block softmax partials
    gemm_nt_pre_async<<<dim3(64, 64), blk, 0, stream>>>(
        Shi, Slo, Khi, Klo, attns, pm, pz, 8192, 8192, 1024);
    // 3) Vt = knowl^T bf16 (overlays dead Khi/Klo)
    transpose_to_bf16<<<dim3(128, 32), blk, 0, stream>>>(knowl, Vt, 8192, 2048);
    // 4) softmax combine + normalize (also emits bf16 attns copy into Ab)
    col_softmax_combine64<<<dim3(32), blk, 0, stream>>>(pm, pz, mf, iz);
    normalize_attn_bf16<<<dim3(65536), blk, 0, stream>>>(attns, mf, iz, Ab);
    // 5) fused = attns @ V == Ab @ Vt^T
    gemm_nt_bf16_async<<<dim3(64, 16), blk, 0, stream>>>(
        Ab, Vt, fused, 8192, 2048, 8192);
}